// Round 10
// baseline (197.676 us; speedup 1.0000x reference)
//
#include <hip/hip_runtime.h>
#include <hip/hip_bf16.h>

// CumulativeLayerNorm fused single-pass v10: x [B=8, C=512, T=16000] f32.
// Block = (batch b, PAIR of 64-t chunks). 512 threads, ~13 KB LDS, VGPR<=64
// => 4 blocks/CU, ALL 1000 blocks co-resident (no dispatch tail, no deadlock).
// Phase A streams both tiles (column sums); ONE lookback per pair (chunk 2p+1
// carry = carry + local total). Spin hidden behind the second tile's stream +
// 3 sibling blocks per CU. Phase C re-reads tiles (L3-hot, within-kernel,
// j1 first = freshest) and nt-stores the normalized output.
// Workspace: W1[B*125] + W2[B*125] u64 {flag,val} (memset 0 each launch).

constexpr int Bb = 8;
constexpr int Cc = 512;
constexpr int Tt = 16000;
constexpr int T4 = Tt / 4;          // 4000
constexpr int TCH = 64;             // t per chunk
constexpr int T4CH = TCH / 4;       // 16
constexpr int NPAIR = Tt / (2 * TCH); // 125 pairs per batch chain
constexpr float EPSF = 1e-8f;

typedef float f32x4 __attribute__((ext_vector_type(4)));

__device__ __forceinline__ unsigned long long pack_av(float v) {
    return (1ull << 32) | (unsigned long long)__float_as_uint(v);
}

__device__ __forceinline__ f32x4 shflx(f32x4 v, int m) {
    f32x4 r;
    r.x = __shfl_xor(v.x, m, 64);
    r.y = __shfl_xor(v.y, m, 64);
    r.z = __shfl_xor(v.z, m, 64);
    r.w = __shfl_xor(v.w, m, 64);
    return r;
}

// Sum aggregates W[chain][0..k-1] in FIXED order (64-lane slices + xor tree)
// -> deterministic. k <= 125 => at most 2 slices.
__device__ __forceinline__ float lookback_sum(const unsigned long long* W,
                                              int chain_base, int k, int lane)
{
    float carry = 0.f;
    #pragma unroll 1
    for (int base = 0; base < k; base += 64) {
        const int j = base + lane;
        float v = 0.f;
        if (j < k) {
            unsigned long long w;
            for (;;) {
                w = __hip_atomic_load(&W[chain_base + j], __ATOMIC_RELAXED,
                                      __HIP_MEMORY_SCOPE_AGENT);
                if (w >> 32) break;
                __builtin_amdgcn_s_sleep(1);
            }
            v = __uint_as_float((unsigned)w);
        }
        #pragma unroll
        for (int m = 1; m < 64; m <<= 1) v += __shfl_xor(v, m, 64);
        carry += v;
    }
    return carry;
}

__global__ __launch_bounds__(512, 8)
void fused_cln_kernel(const float* __restrict__ x,
                      const float* __restrict__ gamma,
                      const float* __restrict__ beta,
                      float* __restrict__ out,
                      unsigned long long* __restrict__ W1,
                      unsigned long long* __restrict__ W2)
{
    const int bid = blockIdx.x;
    const int p = bid >> 3;          // pair 0..124 (p-major: chains advance together)
    const int b = bid & 7;
    const int tid = threadIdx.x;
    const int lane = tid & 63;
    const int wave = tid >> 6;       // 0..7
    const int c_sub = tid >> 4;      // 0..31
    const int t4s   = tid & 15;      // 0..15

    __shared__ f32x4 red_s0[8][16], red_q0[8][16];   // 2 KB each pair
    __shared__ f32x4 red_s1[8][16], red_q1[8][16];
    __shared__ f32x4 mean0_l[16], istd0_l[16], mean1_l[16], istd1_l[16];
    __shared__ float gam[Cc], bet[Cc];

    gam[tid] = gamma[tid];
    bet[tid] = beta[tid];

    const int j0 = 2 * p, j1 = 2 * p + 1;
    const f32x4* xb = (const f32x4*)x + (size_t)(b * Cc + c_sub) * T4 + t4s;

    // ---------- phase A: stream both tiles, column partial sums ----------
    {
        f32x4 ps = 0, pq = 0;
        #pragma unroll
        for (int r = 0; r < 16; ++r) {
            const f32x4 v = xb[j0 * T4CH + (size_t)r * 32 * T4];  // c = c_sub + 32r
            ps += v; pq += v * v;
        }
        ps += shflx(ps, 16); pq += shflx(pq, 16);   // fold the wave's 4 c_subs
        ps += shflx(ps, 32); pq += shflx(pq, 32);
        if (lane < 16) { red_s0[wave][lane] = ps; red_q0[wave][lane] = pq; }
    }
    {
        f32x4 ps = 0, pq = 0;
        #pragma unroll
        for (int r = 0; r < 16; ++r) {
            const f32x4 v = xb[j1 * T4CH + (size_t)r * 32 * T4];
            ps += v; pq += v * v;
        }
        ps += shflx(ps, 16); pq += shflx(pq, 16);
        ps += shflx(ps, 32); pq += shflx(pq, 32);
        if (lane < 16) { red_s1[wave][lane] = ps; red_q1[wave][lane] = pq; }
    }
    __syncthreads();

    // ---------- phase B: wave 0 scans both chunks, ONE lookback per quantity ----------
    if (tid < 64) {
        const bool act = lane < 16;
        const int chain = b * NPAIR;
        const float Cf = (float)Cc;

        f32x4 sv0 = 0, qv0 = 0, sv1 = 0, qv1 = 0;
        if (act) {
            #pragma unroll
            for (int w = 0; w < 8; ++w) {            // fixed order => deterministic
                sv0 += red_s0[w][lane]; qv0 += red_q0[w][lane];
                sv1 += red_s1[w][lane]; qv1 += red_q1[w][lane];
            }
        }

        // s1 scan, chunk0
        const float a0 = sv0.x, a1 = a0 + sv0.y, a2 = a1 + sv0.z, a3 = a2 + sv0.w;
        float sc0 = act ? a3 : 0.f;
        const float ls0 = sc0;
        #pragma unroll
        for (int off = 1; off < 16; off <<= 1) {
            const float n = __shfl_up(sc0, off, 64);
            if (lane >= off) sc0 += n;
        }
        const float T0 = __shfl(sc0, 15, 64);
        const float ex0 = sc0 - ls0;

        // s1 scan, chunk1
        const float e0 = sv1.x, e1 = e0 + sv1.y, e2 = e1 + sv1.z, e3 = e2 + sv1.w;
        float sc1 = act ? e3 : 0.f;
        const float ls1 = sc1;
        #pragma unroll
        for (int off = 1; off < 16; off <<= 1) {
            const float n = __shfl_up(sc1, off, 64);
            if (lane >= off) sc1 += n;
        }
        const float T1 = __shfl(sc1, 15, 64);
        const float ex1 = sc1 - ls1;

        if (lane == 0)
            __hip_atomic_store(&W1[chain + p], pack_av(T0 + T1), __ATOMIC_RELAXED,
                               __HIP_MEMORY_SCOPE_AGENT);
        const float carry1 = lookback_sum(W1, chain, p, lane);

        // chunk0: means + s2
        const float tb0 = (float)(j0 * TCH + lane * 4);
        f32x4 cnt0;
        cnt0.x = Cf * (tb0 + 1.f); cnt0.y = Cf * (tb0 + 2.f);
        cnt0.z = Cf * (tb0 + 3.f); cnt0.w = Cf * (tb0 + 4.f);
        f32x4 cs0;
        cs0.x = carry1 + ex0 + a0; cs0.y = carry1 + ex0 + a1;
        cs0.z = carry1 + ex0 + a2; cs0.w = carry1 + ex0 + a3;
        const f32x4 mn0 = cs0 / cnt0;
        if (act) mean0_l[lane] = mn0;
        f32x4 s20 = qv0 - 2.f * mn0 * sv0 + Cf * mn0 * mn0;
        if (!act) s20 = 0.f;

        const float d0 = s20.x, d1 = d0 + s20.y, d2 = d1 + s20.z, d3 = d2 + s20.w;
        float u0 = act ? d3 : 0.f;
        const float lu0 = u0;
        #pragma unroll
        for (int off = 1; off < 16; off <<= 1) {
            const float n = __shfl_up(u0, off, 64);
            if (lane >= off) u0 += n;
        }
        const float S0 = __shfl(u0, 15, 64);
        const float exs0 = u0 - lu0;

        // chunk1: means + s2 (carry for chunk1 = carry1 + T0, no extra lookback)
        const float carry1b = carry1 + T0;
        const float tb1 = (float)(j1 * TCH + lane * 4);
        f32x4 cnt1;
        cnt1.x = Cf * (tb1 + 1.f); cnt1.y = Cf * (tb1 + 2.f);
        cnt1.z = Cf * (tb1 + 3.f); cnt1.w = Cf * (tb1 + 4.f);
        f32x4 cs1;
        cs1.x = carry1b + ex1 + e0; cs1.y = carry1b + ex1 + e1;
        cs1.z = carry1b + ex1 + e2; cs1.w = carry1b + ex1 + e3;
        const f32x4 mn1 = cs1 / cnt1;
        if (act) mean1_l[lane] = mn1;
        f32x4 s21 = qv1 - 2.f * mn1 * sv1 + Cf * mn1 * mn1;
        if (!act) s21 = 0.f;

        const float f0 = s21.x, f1 = f0 + s21.y, f2 = f1 + s21.z, f3 = f2 + s21.w;
        float u1 = act ? f3 : 0.f;
        const float lu1 = u1;
        #pragma unroll
        for (int off = 1; off < 16; off <<= 1) {
            const float n = __shfl_up(u1, off, 64);
            if (lane >= off) u1 += n;
        }
        const float S1 = __shfl(u1, 15, 64);
        const float exs1 = u1 - lu1;

        if (lane == 0)
            __hip_atomic_store(&W2[chain + p], pack_av(S0 + S1), __ATOMIC_RELAXED,
                               __HIP_MEMORY_SCOPE_AGENT);
        const float carry2 = lookback_sum(W2, chain, p, lane);

        if (act) {
            f32x4 cv0;
            cv0.x = carry2 + exs0 + d0; cv0.y = carry2 + exs0 + d1;
            cv0.z = carry2 + exs0 + d2; cv0.w = carry2 + exs0 + d3;
            const f32x4 var0 = cv0 / cnt0;
            f32x4 is0;
            is0.x = rsqrtf(var0.x + EPSF); is0.y = rsqrtf(var0.y + EPSF);
            is0.z = rsqrtf(var0.z + EPSF); is0.w = rsqrtf(var0.w + EPSF);
            istd0_l[lane] = is0;

            const float carry2b = carry2 + S0;
            f32x4 cv1;
            cv1.x = carry2b + exs1 + f0; cv1.y = carry2b + exs1 + f1;
            cv1.z = carry2b + exs1 + f2; cv1.w = carry2b + exs1 + f3;
            const f32x4 var1 = cv1 / cnt1;
            f32x4 is1;
            is1.x = rsqrtf(var1.x + EPSF); is1.y = rsqrtf(var1.y + EPSF);
            is1.z = rsqrtf(var1.z + EPSF); is1.w = rsqrtf(var1.w + EPSF);
            istd1_l[lane] = is1;
        }
    }
    __syncthreads();

    // ---------- phase C: re-read tiles (L3-hot, j1 first = freshest), normalize ----------
    f32x4* ob = (f32x4*)out + (size_t)(b * Cc + c_sub) * T4 + t4s;
    {
        const f32x4 m4 = mean1_l[t4s], s4 = istd1_l[t4s];
        #pragma unroll
        for (int r = 0; r < 16; ++r) {
            const int c = c_sub + 32 * r;
            const f32x4 xv = xb[j1 * T4CH + (size_t)r * 32 * T4];
            const f32x4 sg = s4 * gam[c];
            const f32x4 o4 = bet[c] - m4 * sg;
            __builtin_nontemporal_store(xv * sg + o4, &ob[j1 * T4CH + (size_t)r * 32 * T4]);
        }
    }
    {
        const f32x4 m4 = mean0_l[t4s], s4 = istd0_l[t4s];
        #pragma unroll
        for (int r = 0; r < 16; ++r) {
            const int c = c_sub + 32 * r;
            const f32x4 xv = xb[j0 * T4CH + (size_t)r * 32 * T4];
            const f32x4 sg = s4 * gam[c];
            const f32x4 o4 = bet[c] - m4 * sg;
            __builtin_nontemporal_store(xv * sg + o4, &ob[j0 * T4CH + (size_t)r * 32 * T4]);
        }
    }
}

extern "C" void kernel_launch(void* const* d_in, const int* in_sizes, int n_in,
                              void* d_out, int out_size, void* d_ws, size_t ws_size,
                              hipStream_t stream) {
    const float* x     = (const float*)d_in[0];
    const float* gamma = (const float*)d_in[1];
    const float* beta  = (const float*)d_in[2];
    float* out = (float*)d_out;

    unsigned long long* W1 = (unsigned long long*)d_ws;
    unsigned long long* W2 = W1 + (size_t)Bb * NPAIR;

    // clear lookback state every launch (ws is NOT re-poisoned between replays)
    hipMemsetAsync(d_ws, 0, 2 * (size_t)Bb * NPAIR * sizeof(unsigned long long), stream);

    fused_cln_kernel<<<Bb * NPAIR, 512, 0, stream>>>(x, gamma, beta, out, W1, W2);
}

// Round 11
// 125.481 us; speedup vs baseline: 1.5753x; 1.5753x over previous
//
#include <hip/hip_runtime.h>
#include <hip/hip_bf16.h>

// CumulativeLayerNorm fused single-pass v11: x [B=8, C=512, T=16000] f32.
// One block per (batch b, 128-t chunk), 1024 threads (R5 geometry = best).
// ONE publication + ONE spin per block: each block publishes
// (total1, A, B, D) right after phase A, where the chunk's s2-aggregate as a
// function of the incoming carry is EXACTLY A + B*carry + D*carry^2 (A,B,D
// local). The lookback prefixes predecessors' total1 in fixed order and
// evaluates their quadratics locally => both carries from a single spin.
// Phase C re-reads the tile (proven 100% L3-hit when temporally local, R8)
// and nt-stores the output.
// Workspace: W[B*125][4] u64 {flag|f32} words (memset 0 each launch).

constexpr int Bb = 8;
constexpr int Cc = 512;
constexpr int Tt = 16000;
constexpr int T4 = Tt / 4;          // 4000
constexpr int TCH = 128;            // t per chunk
constexpr int T4CH = TCH / 4;       // 32
constexpr int NCHK = Tt / TCH;      // 125
constexpr float EPSF = 1e-8f;

typedef float f32x4 __attribute__((ext_vector_type(4)));

__device__ __forceinline__ unsigned long long pack_av(float v) {
    return (1ull << 32) | (unsigned long long)__float_as_uint(v);
}

__device__ __forceinline__ f32x4 shflx(f32x4 v, int m) {
    f32x4 r;
    r.x = __shfl_xor(v.x, m, 64);
    r.y = __shfl_xor(v.y, m, 64);
    r.z = __shfl_xor(v.z, m, 64);
    r.w = __shfl_xor(v.w, m, 64);
    return r;
}

__device__ __forceinline__ float spin_load(const unsigned long long* p) {
    unsigned long long w;
    for (;;) {
        w = __hip_atomic_load(p, __ATOMIC_RELAXED, __HIP_MEMORY_SCOPE_AGENT);
        if (w >> 32) break;
        __builtin_amdgcn_s_sleep(1);
    }
    return __uint_as_float((unsigned)w);
}

__global__ __launch_bounds__(1024)
void fused_cln_kernel(const float* __restrict__ x,
                      const float* __restrict__ gamma,
                      const float* __restrict__ beta,
                      float* __restrict__ out,
                      unsigned long long* __restrict__ W)
{
    const int bid = blockIdx.x;
    const int k = bid >> 3;          // chunk 0..124 (k-major: chains advance together)
    const int b = bid & 7;
    const int tid = threadIdx.x;
    const int lane = tid & 63;
    const int wave = tid >> 6;       // 0..15
    const int c_sub = tid >> 5;      // 0..31
    const int t4s   = tid & 31;      // 0..31
    const float Cf = (float)Cc;

    __shared__ f32x4 red_s[16][32], red_q[16][32];   // [wave][t4s] 16 KB
    __shared__ f32x4 mean_l[32], istd_l[32];
    __shared__ float gam[Cc], bet[Cc];

    if (tid < Cc) { gam[tid] = gamma[tid]; bet[tid] = beta[tid]; }

    // ---------- phase A: stream tile, column partial sums ----------
    const f32x4* xb = (const f32x4*)x + (size_t)(b * Cc + c_sub) * T4 + k * T4CH + t4s;
    f32x4 ps = 0, pq = 0;
    #pragma unroll
    for (int r = 0; r < 16; ++r) {
        const f32x4 v = xb[(size_t)r * 32 * T4];     // c = c_sub + 32*r
        ps += v;
        pq += v * v;
    }
    ps += shflx(ps, 32);             // fold the wave's c_sub pair
    pq += shflx(pq, 32);
    if (lane < 32) { red_s[wave][lane] = ps; red_q[wave][lane] = pq; }
    __syncthreads();

    // ---------- phase B: wave 0 — publish (total1,A,B,D), ONE spin, scan ----------
    if (tid < 64) {
        const bool act = lane < 32;
        const int chain = b * NCHK;

        f32x4 sv = 0, qv = 0;
        if (act) {
            #pragma unroll
            for (int w = 0; w < 16; ++w) {           // fixed order => deterministic
                sv += red_s[w][lane];
                qv += red_q[w][lane];
            }
        }

        // local inclusive prefix of s1 over the chunk
        const float c0 = sv.x, c1 = c0 + sv.y, c2 = c1 + sv.z, c3 = c2 + sv.w;
        const float lsum = act ? c3 : 0.f;
        float sc = lsum;
        #pragma unroll
        for (int off = 1; off < 64; off <<= 1) {
            const float n = __shfl_up(sc, off, 64);
            if (lane >= off) sc += n;
        }
        const float total1 = __shfl(sc, 31, 64);
        const float ex1 = sc - lsum;                 // exclusive prefix (valid for act)

        // counts, reciprocals, local prefixes
        const float t0f = (float)(k * TCH + lane * 4);
        f32x4 cnt;
        cnt.x = Cf * (t0f + 1.f); cnt.y = Cf * (t0f + 2.f);
        cnt.z = Cf * (t0f + 3.f); cnt.w = Cf * (t0f + 4.f);
        const f32x4 inv = 1.f / cnt;
        f32x4 l;
        l.x = ex1 + c0; l.y = ex1 + c1; l.z = ex1 + c2; l.w = ex1 + c3;

        // quadratic aggregate coefficients: sum_chunk s2(carry) = A + B*c + D*c^2
        f32x4 Ai = qv - 2.f * sv * l * inv + Cf * l * l * inv * inv;
        f32x4 Bi = -2.f * sv * inv + 2.f * Cf * l * inv * inv;
        f32x4 Di = Cf * inv * inv;
        float As = act ? (Ai.x + Ai.y + Ai.z + Ai.w) : 0.f;
        float Bs = act ? (Bi.x + Bi.y + Bi.z + Bi.w) : 0.f;
        float Ds = act ? (Di.x + Di.y + Di.z + Di.w) : 0.f;
        #pragma unroll
        for (int m = 1; m < 64; m <<= 1) {
            As += __shfl_xor(As, m, 64);
            Bs += __shfl_xor(Bs, m, 64);
            Ds += __shfl_xor(Ds, m, 64);
        }

        if (lane == 0) {
            unsigned long long* Wk = W + (size_t)(chain + k) * 4;
            __hip_atomic_store(Wk + 0, pack_av(total1), __ATOMIC_RELAXED, __HIP_MEMORY_SCOPE_AGENT);
            __hip_atomic_store(Wk + 1, pack_av(As),     __ATOMIC_RELAXED, __HIP_MEMORY_SCOPE_AGENT);
            __hip_atomic_store(Wk + 2, pack_av(Bs),     __ATOMIC_RELAXED, __HIP_MEMORY_SCOPE_AGENT);
            __hip_atomic_store(Wk + 3, pack_av(Ds),     __ATOMIC_RELAXED, __HIP_MEMORY_SCOPE_AGENT);
        }

        // ---- single lookback: both carries from one spin ----
        float carry1 = 0.f, carry2 = 0.f;
        #pragma unroll 1
        for (int base = 0; base < k; base += 64) {
            const int j = base + lane;
            float t1 = 0.f, Aj = 0.f, Bj = 0.f, Dj = 0.f;
            if (j < k) {
                const unsigned long long* Wj = W + (size_t)(chain + j) * 4;
                t1 = spin_load(Wj + 0);
                Aj = spin_load(Wj + 1);
                Bj = spin_load(Wj + 2);
                Dj = spin_load(Wj + 3);
            }
            // exclusive prefix of t1 across the slice (fixed order)
            float scn = t1;
            #pragma unroll
            for (int off = 1; off < 64; off <<= 1) {
                const float n = __shfl_up(scn, off, 64);
                if (lane >= off) scn += n;
            }
            const float slice_total = __shfl(scn, 63, 64);
            const float cj = carry1 + (scn - t1);    // carry1 entering pred j
            float s2j = Aj + Bj * cj + Dj * cj * cj; // pred j's s2-aggregate
            #pragma unroll
            for (int m = 1; m < 64; m <<= 1) s2j += __shfl_xor(s2j, m, 64);
            carry2 += s2j;
            carry1 += slice_total;
        }

        // ---- finish: means, in-chunk s2 scan, istd ----
        f32x4 cs1;
        cs1.x = carry1 + l.x; cs1.y = carry1 + l.y;
        cs1.z = carry1 + l.z; cs1.w = carry1 + l.w;
        const f32x4 mn = cs1 / cnt;
        if (act) mean_l[lane] = mn;

        f32x4 s2 = qv - 2.f * mn * sv + Cf * mn * mn;
        if (!act) s2 = 0.f;
        const float d0 = s2.x, d1 = d0 + s2.y, d2 = d1 + s2.z, d3 = d2 + s2.w;
        const float lsum2 = act ? d3 : 0.f;
        float sc2 = lsum2;
        #pragma unroll
        for (int off = 1; off < 64; off <<= 1) {
            const float n = __shfl_up(sc2, off, 64);
            if (lane >= off) sc2 += n;
        }
        const float ex2 = sc2 - lsum2;

        if (act) {
            f32x4 cv;
            cv.x = carry2 + ex2 + d0; cv.y = carry2 + ex2 + d1;
            cv.z = carry2 + ex2 + d2; cv.w = carry2 + ex2 + d3;
            const f32x4 var = cv / cnt;
            f32x4 is;
            is.x = rsqrtf(var.x + EPSF); is.y = rsqrtf(var.y + EPSF);
            is.z = rsqrtf(var.z + EPSF); is.w = rsqrtf(var.w + EPSF);
            istd_l[lane] = is;
        }
    }
    __syncthreads();

    // ---------- phase C: re-read tile (L3-hot), normalize, stream out ----------
    const f32x4 m4 = mean_l[t4s];
    const f32x4 s4 = istd_l[t4s];
    f32x4* ob = (f32x4*)out + (size_t)(b * Cc + c_sub) * T4 + k * T4CH + t4s;
    #pragma unroll
    for (int r = 0; r < 16; ++r) {
        const int c = c_sub + 32 * r;
        const f32x4 xv   = xb[(size_t)r * 32 * T4];
        const f32x4 sg   = s4 * gam[c];
        const f32x4 off4 = bet[c] - m4 * sg;
        __builtin_nontemporal_store(xv * sg + off4, &ob[(size_t)r * 32 * T4]);
    }
}

extern "C" void kernel_launch(void* const* d_in, const int* in_sizes, int n_in,
                              void* d_out, int out_size, void* d_ws, size_t ws_size,
                              hipStream_t stream) {
    const float* x     = (const float*)d_in[0];
    const float* gamma = (const float*)d_in[1];
    const float* beta  = (const float*)d_in[2];
    float* out = (float*)d_out;

    unsigned long long* W = (unsigned long long*)d_ws;

    // clear lookback state every launch (ws is NOT re-poisoned between replays)
    hipMemsetAsync(d_ws, 0, (size_t)Bb * NCHK * 4 * sizeof(unsigned long long), stream);

    fused_cln_kernel<<<Bb * NCHK, 1024, 0, stream>>>(x, gamma, beta, out, W);
}